// Round 6
// baseline (395.901 us; speedup 1.0000x reference)
//
#include <hip/hip_runtime.h>
#include <stdint.h>

// MegatronAttention: B=2, S=2048, H=2048, NH=16, DH=128.
// KEY INSIGHT: reference einsum 'bhqk,bhkd->bhkd' sums over q ->
//   values[b,h,k,d] = colsum_q(probs)[b,h,k] * v[b,h,k,d].
// Pipeline: convert->bf16, QKV GEMM (scatter epilogue, Q pre-scaled by
// 1/sqrt(d)*log2e), l-pass (writes 1/rowsum), cs-pass (weighted col sums
// + fused V scale), output GEMM.
// Anchor: qkv8 dispatch time (106-109 us at normal clock) calibrates
// session speed; R9's slow session (anchor 131) masked what looks like a
// real attn-256 win (clock-corrected rest ~222 us vs 250 for attn-128).
// R10: outg ring-3 was neutral-to-worse than the BK=64 drain form.
// R11: best-proven recombination: qkv8 (R6) + attn-256 (R9, clean-session
// re-test) + outg drain BK=64 3/CU (R5/R8) + converts.

typedef __bf16 bf16_t;
typedef __bf16 bf16x8v __attribute__((ext_vector_type(8)));
typedef __bf16 bf16x4v __attribute__((ext_vector_type(4)));
typedef float  f32x4v  __attribute__((ext_vector_type(4)));

#define DEVINL __device__ __forceinline__

// async global->LDS DMA, 16B per lane. LDS dest is wave-uniform base;
// HW writes lane i's data at base + i*16. Respects exec mask.
DEVINL void gll16(const void* g, void* lds_wave_uniform_base) {
    __builtin_amdgcn_global_load_lds(
        (__attribute__((address_space(1))) void*)g,
        (__attribute__((address_space(3))) void*)lds_wave_uniform_base,
        16, 0, 0);
}

#define WAITVM(n) asm volatile("s_waitcnt vmcnt(" #n ")" ::: "memory")
#define WAITLG0() asm volatile("s_waitcnt lgkmcnt(0)" ::: "memory")
#define FENCE()   asm volatile("" ::: "memory")

// ---------------------------------------------------------------- converts
__global__ void conv_x_k(const float* __restrict__ in, bf16_t* __restrict__ out) {
    size_t i = ((size_t)blockIdx.x * 256 + threadIdx.x) * 4;
    float4 v = *reinterpret_cast<const float4*>(in + i);
    bf16x4v o;
    o[0] = (__bf16)v.x; o[1] = (__bf16)v.y; o[2] = (__bf16)v.z; o[3] = (__bf16)v.w;
    *reinterpret_cast<bf16x4v*>(out + i) = o;
}

// out[n][k] = (bf16) in[k][n]   (in: K x N fp32, out: N x K bf16)
__global__ void conv_wT_k(const float* __restrict__ in, bf16_t* __restrict__ out,
                          int K, int N) {
    __shared__ float t[64][33];
    int n0 = blockIdx.x * 32, k0 = blockIdx.y * 64;
    int tn = threadIdx.x & 31, tk = threadIdx.x >> 5;   // tk in 0..7
#pragma unroll
    for (int i = 0; i < 64; i += 8)
        t[tk + i][tn] = in[(size_t)(k0 + tk + i) * N + n0 + tn];
    __syncthreads();
    int n = threadIdx.x >> 3, kg = threadIdx.x & 7;
    bf16x8v o;
#pragma unroll
    for (int i = 0; i < 8; ++i) o[i] = (__bf16)t[kg * 8 + i][n];
    *reinterpret_cast<bf16x8v*>(out + (size_t)(n0 + n) * K + k0 + kg * 8) = o;
}

// ---------------------------------------------------------------- QKV GEMM
// C[4096,6144] = Xb @ WqkvT^T. 256x192 tile, BK=32, 8 waves (2Mx4N),
// 4-buffer LDS ring (112 KiB), counted vmcnt(8), setprio. R6 proven form.
__launch_bounds__(512, 2)
__global__ void qkv8_k(const bf16_t* __restrict__ A, const bf16_t* __restrict__ Bm,
                       bf16_t* __restrict__ Qb, bf16_t* __restrict__ Kb,
                       bf16_t* __restrict__ Vb)
{
    extern __shared__ __align__(16) char smem[];   // 114688 B
    constexpr int K = 2048, NT = 64;               // K-tiles of 32
    constexpr int BUF = 28672;                     // 448*64 B per buffer
    const int tid  = threadIdx.x;
    const int lane = tid & 63, wave = tid >> 6;
    const int quad = lane >> 4, l15 = lane & 15;
    const int rowBase = blockIdx.y * 256, colBase = blockIdx.x * 192;
    const int wr = wave >> 2, wc = wave & 3;
    const bool stager = (wave < 7);                // threads 0..447

    const bf16_t* sp[4]; uint32_t sdo[4];
#pragma unroll
    for (int r = 0; r < 4; ++r) {
        int row = r * 112 + (tid >> 2);
        if (row > 447) row = 447;
        int j  = tid & 3;
        int cc = j ^ ((row >> 1) & 3);
        const bf16_t* base = (row < 256)
            ? (A  + (size_t)(rowBase + row) * K)
            : (Bm + (size_t)(colBase + row - 256) * K);
        sp[r]  = base + cc * 8;
        sdo[r] = (uint32_t)(r * 7168 + wave * 1024);
    }
    uint32_t aoff[8], boff[3];
#pragma unroll
    for (int ti = 0; ti < 8; ++ti) {
        int m = wr * 128 + ti * 16 + l15;
        aoff[ti] = (uint32_t)(m * 64 + ((quad ^ ((m >> 1) & 3)) << 4));
    }
#pragma unroll
    for (int tj = 0; tj < 3; ++tj) {
        int rb = 256 + wc * 48 + tj * 16 + l15;
        boff[tj] = (uint32_t)(rb * 64 + ((quad ^ ((rb >> 1) & 3)) << 4));
    }

    if (stager) {
#pragma unroll
        for (int tt = 0; tt < 3; ++tt)
#pragma unroll
            for (int r = 0; r < 4; ++r)
                gll16(sp[r] + tt * 32, smem + tt * BUF + sdo[r]);
    }

    f32x4v acc[8][3] = {};

    auto do_tile = [&](int t, bool stage_on) {
        WAITLG0();
        __builtin_amdgcn_s_barrier();
        FENCE();
        const char* bp = smem + (size_t)(t & 3) * BUF;
        char*       np = smem + (size_t)((t + 3) & 3) * BUF;
        if (stage_on && stager) {
            gll16(sp[0] + (t + 3) * 32, np + sdo[0]);
            gll16(sp[1] + (t + 3) * 32, np + sdo[1]);
        }
        bf16x8v bv[3], av[4];
#pragma unroll
        for (int tj = 0; tj < 3; ++tj) bv[tj] = *(const bf16x8v*)(bp + boff[tj]);
#pragma unroll
        for (int ti = 0; ti < 4; ++ti) av[ti] = *(const bf16x8v*)(bp + aoff[ti]);
        __builtin_amdgcn_s_setprio(1);
#pragma unroll
        for (int ti = 0; ti < 4; ++ti)
#pragma unroll
            for (int tj = 0; tj < 3; ++tj)
                acc[ti][tj] = __builtin_amdgcn_mfma_f32_16x16x32_bf16(
                                  av[ti], bv[tj], acc[ti][tj], 0, 0, 0);
        __builtin_amdgcn_s_setprio(0);
        if (stage_on && stager) {
            gll16(sp[2] + (t + 3) * 32, np + sdo[2]);
            gll16(sp[3] + (t + 3) * 32, np + sdo[3]);
        }
#pragma unroll
        for (int ti = 0; ti < 4; ++ti) av[ti] = *(const bf16x8v*)(bp + aoff[4 + ti]);
        __builtin_amdgcn_s_setprio(1);
#pragma unroll
        for (int ti = 0; ti < 4; ++ti)
#pragma unroll
            for (int tj = 0; tj < 3; ++tj)
                acc[4 + ti][tj] = __builtin_amdgcn_mfma_f32_16x16x32_bf16(
                                      av[ti], bv[tj], acc[4 + ti][tj], 0, 0, 0);
        __builtin_amdgcn_s_setprio(0);
    };

    for (int t = 0; t < NT - 2; ++t) {
        WAITVM(8);
        do_tile(t, t < NT - 3);
    }
    WAITVM(4);
    do_tile(NT - 2, false);
    WAITVM(0);
    do_tile(NT - 1, false);

    constexpr float QS = 0.08838834764831845f * 1.44269504088896341f;
#pragma unroll
    for (int ti = 0; ti < 8; ++ti)
#pragma unroll
        for (int tj = 0; tj < 3; ++tj)
#pragma unroll
            for (int r = 0; r < 4; ++r) {
                int m = rowBase + wr * 128 + ti * 16 + quad * 4 + r;
                int n = colBase + wc * 48 + tj * 16 + l15;
                float v = acc[ti][tj][r];
                int b = m >> 11, s = m & 2047;
                int which = n >> 11, hd = n & 2047;
                if (which == 2) {
                    Vb[(size_t)m * 2048 + hd] = (__bf16)v;        // token-major
                } else {
                    if (which == 0) v *= QS;                      // fold softmax scale
                    size_t idx = ((size_t)((b << 4) + (hd >> 7)) * 2048 + s) * 128
                                 + (hd & 127);
                    if (which == 0) Qb[idx] = (__bf16)v; else Kb[idx] = (__bf16)v;
                }
            }
}

// ---------------------------------------------------------------- out GEMM
// Proven R5/R8 form: 128x128 tile, BK=64, static 32 KiB LDS, 3 blocks/CU,
// drain barriers. C[4096,2048] = Vb @ WoT^T, fp32 out.
__launch_bounds__(256, 3)
__global__ void outg_k(const bf16_t* __restrict__ A, const bf16_t* __restrict__ Bm,
                       float* __restrict__ outF)
{
    __shared__ __align__(16) bf16_t sA[128 * 64];   // 16 KiB
    __shared__ __align__(16) bf16_t sB[128 * 64];
    constexpr int K = 2048;
    const int tid  = threadIdx.x;
    const int lane = tid & 63, wave = tid >> 6;
    const int quad = lane >> 4, l15 = lane & 15;
    const int rowBase = blockIdx.y * 128, colBase = blockIdx.x * 128;
    const int wr0 = (wave >> 1) * 64, wc0 = (wave & 1) * 64;

    const bf16_t* gA[4]; const bf16_t* gB[4]; uint32_t loff[4];
#pragma unroll
    for (int r = 0; r < 4; ++r) {
        int s = r * 256 + wave * 64 + lane;
        int row = s >> 3, j = s & 7;
        int cc = j ^ (row & 7);
        gA[r] = A  + (size_t)(rowBase + row) * K + cc * 8;
        gB[r] = Bm + (size_t)(colBase + row) * K + cc * 8;
        loff[r] = (uint32_t)(r * 256 + wave * 64) * 16;
    }
    int aoff[2][4], boff[2][4];   // [kstep][t] LDS elem offsets
#pragma unroll
    for (int ks = 0; ks < 2; ++ks)
#pragma unroll
        for (int t = 0; t < 4; ++t) {
            int m = wr0 + t * 16 + l15;
            aoff[ks][t] = (m * 8 + ((ks * 4 + quad) ^ (m & 7))) * 8;
            int n = wc0 + t * 16 + l15;
            boff[ks][t] = (n * 8 + ((ks * 4 + quad) ^ (n & 7))) * 8;
        }

    f32x4v acc[4][4] = {};
    for (int kt = 0; kt < K / 64; ++kt) {
        __syncthreads();
#pragma unroll
        for (int r = 0; r < 4; ++r) {
            gll16(gA[r] + kt * 64, (char*)sA + loff[r]);
            gll16(gB[r] + kt * 64, (char*)sB + loff[r]);
        }
        __syncthreads();
#pragma unroll
        for (int ks = 0; ks < 2; ++ks) {
            bf16x8v av[4], bv[4];
#pragma unroll
            for (int t = 0; t < 4; ++t) av[t] = *reinterpret_cast<const bf16x8v*>(sA + aoff[ks][t]);
#pragma unroll
            for (int t = 0; t < 4; ++t) bv[t] = *reinterpret_cast<const bf16x8v*>(sB + boff[ks][t]);
#pragma unroll
            for (int ti = 0; ti < 4; ++ti)
#pragma unroll
                for (int tj = 0; tj < 4; ++tj)
                    acc[ti][tj] = __builtin_amdgcn_mfma_f32_16x16x32_bf16(
                                      av[ti], bv[tj], acc[ti][tj], 0, 0, 0);
        }
    }

#pragma unroll
    for (int ti = 0; ti < 4; ++ti)
#pragma unroll
        for (int tj = 0; tj < 4; ++tj)
#pragma unroll
            for (int r = 0; r < 4; ++r) {
                int m = rowBase + wr0 + ti * 16 + quad * 4 + r;
                int n = colBase + wc0 + tj * 16 + l15;
                outF[(size_t)m * 2048 + n] = acc[ti][tj][r];
            }
}

// ---------------------------------------------------------------- attention
// R9 form, re-tested at normal clock: block owns 256 resident rows (frags
// in VGPR across 8 waves), sweeps all 2048 streamed rows in 32 x 64-row
// tiles through a 4-buffer LDS ring with counted vmcnt. Grid 256 (8x32),
// 512 threads, 64 KiB ring. Wave = (rg, sh): rg = wave>>1 owns resident
// rows rg*64..+63; sh = wave&1 streams half-tile sh*32..+31.
// Swizzle: cc = j ^ (row&7). Halves streamed K/Q refetch vs 128-resident.

__launch_bounds__(512, 4)
__global__ void attn_l_k(const bf16_t* __restrict__ Qb, const bf16_t* __restrict__ Kb,
                         float* __restrict__ rl)
{
    extern __shared__ __align__(16) char smem[];   // 4 x 16384 = 65536 B
    constexpr int BUF = 16384;
    const int tid  = threadIdx.x;
    const int lane = tid & 63, wave = tid >> 6;
    const int quad = lane >> 4, l15 = lane & 15;
    const int qt = blockIdx.x, bh = blockIdx.y;
    const bf16_t* Qg = Qb + (size_t)bh * 2048 * 128 + (size_t)qt * 256 * 128;
    const bf16_t* Kg = Kb + (size_t)bh * 2048 * 128;
    const int rg = wave >> 1;           // resident row group (0..3)
    const int wr0 = rg * 64;
    const int wc0 = (wave & 1) * 32;    // streamed half-tile

    // staging map: 2 slots/thread per 16 KiB buffer (1024 slots of 16B)
    int srow[2], scc[2]; uint32_t soff[2];
#pragma unroll
    for (int r = 0; r < 2; ++r) {
        int s = r * 512 + wave * 64 + lane;
        srow[r] = s >> 4; int j = s & 15;
        scc[r] = j ^ (srow[r] & 7);
        soff[r] = (uint32_t)(r * 512 + wave * 64) * 16;
    }
    // stage resident Q (256 rows, 64 KiB) into buffers 0..3
#pragma unroll
    for (int b = 0; b < 4; ++b)
#pragma unroll
        for (int r = 0; r < 2; ++r)
            gll16(Qg + (size_t)(b * 64 + srow[r]) * 128 + scc[r] * 8,
                  smem + b * BUF + soff[r]);
    __syncthreads();
    const bf16_t* qlds = (const bf16_t*)smem;
    bf16x8v qf[4][4];   // [kb][ti] : 64 VGPR, invariant over the sweep
#pragma unroll
    for (int kb = 0; kb < 4; ++kb)
#pragma unroll
        for (int t = 0; t < 4; ++t) {
            int m = wr0 + t * 16 + l15;   // 0..255 (buffers contiguous)
            qf[kb][t] = *reinterpret_cast<const bf16x8v*>(
                qlds + m * 128 + ((kb * 4 + quad) ^ (m & 7)) * 8);
        }
    __syncthreads();    // Q reads drained before K overwrites
    // prologue: stage K tiles 0,1,2 (2 loads/thread/tile)
#pragma unroll
    for (int tt = 0; tt < 3; ++tt)
#pragma unroll
        for (int r = 0; r < 2; ++r)
            gll16(Kg + (size_t)(tt * 64 + srow[r]) * 128 + scc[r] * 8,
                  smem + tt * BUF + soff[r]);

    float lsum[4][4] = {};
    auto do_tile = [&](int t, bool stage_on) {
        WAITLG0();
        __builtin_amdgcn_s_barrier();
        FENCE();
        const bf16_t* cb = (const bf16_t*)(smem + (size_t)(t & 3) * BUF);
        if (stage_on) {
            char* tgt = smem + (size_t)((t + 3) & 3) * BUF;
#pragma unroll
            for (int r = 0; r < 2; ++r)
                gll16(Kg + (size_t)((t + 3) * 64 + srow[r]) * 128 + scc[r] * 8,
                      tgt + soff[r]);
        }
        f32x4v sc[4][2] = {};
#pragma unroll
        for (int kb = 0; kb < 4; ++kb) {
            int ccq = kb * 4 + quad;
            bf16x8v bv[2];
#pragma unroll
            for (int tj = 0; tj < 2; ++tj) {
                int n = wc0 + tj * 16 + l15;   // 0..63
                bv[tj] = *reinterpret_cast<const bf16x8v*>(
                    cb + (n * 16 + (ccq ^ (n & 7))) * 8);
            }
            __builtin_amdgcn_s_setprio(1);
#pragma unroll
            for (int ti = 0; ti < 4; ++ti)
#pragma unroll
                for (int tj = 0; tj < 2; ++tj)
                    sc[ti][tj] = __builtin_amdgcn_mfma_f32_16x16x32_bf16(
                                     qf[kb][ti], bv[tj], sc[ti][tj], 0, 0, 0);
            __builtin_amdgcn_s_setprio(0);
        }
#pragma unroll
        for (int ti = 0; ti < 4; ++ti)
#pragma unroll
            for (int r = 0; r < 4; ++r)
                lsum[ti][r] += __builtin_amdgcn_exp2f(sc[ti][0][r])
                             + __builtin_amdgcn_exp2f(sc[ti][1][r]);
    };

    for (int t = 0; t < 29; ++t) {
        WAITVM(4);
        do_tile(t, true);
    }
    WAITVM(4); do_tile(29, false);
    WAITVM(2); do_tile(30, false);
    WAITVM(0); do_tile(31, false);

    // reduce across l15 (cols) then across sh wave pairs via LDS
    __syncthreads();
    float* l_sh = (float*)smem;
    if (tid < 256) l_sh[tid] = 0.f;
    __syncthreads();
#pragma unroll
    for (int ti = 0; ti < 4; ++ti)
#pragma unroll
        for (int r = 0; r < 4; ++r) {
            float v = lsum[ti][r];
            v += __shfl_xor(v, 1); v += __shfl_xor(v, 2);
            v += __shfl_xor(v, 4); v += __shfl_xor(v, 8);
            if (l15 == 0) atomicAdd(&l_sh[wr0 + ti * 16 + quad * 4 + r], v);
        }
    __syncthreads();
    if (tid < 256)
        rl[(size_t)bh * 2048 + qt * 256 + tid] = 1.0f / l_sh[tid];
}

__launch_bounds__(512, 4)
__global__ void attn_cs_k(const bf16_t* __restrict__ Qb, const bf16_t* __restrict__ Kb,
                          const float* __restrict__ rl, bf16_t* __restrict__ Vb)
{
    // layout: [0,65536) = 4 x 16 KiB Q-tile ring; [65536,66560) = 4 x 256B rl ring
    extern __shared__ __align__(16) char smem[];
    constexpr int BUF = 16384, RLOFF = 65536;
    const int tid  = threadIdx.x;
    const int lane = tid & 63, wave = tid >> 6;
    const int quad = lane >> 4, l15 = lane & 15;
    const int kt = blockIdx.x, bh = blockIdx.y;
    const bf16_t* Kg = Kb + (size_t)bh * 2048 * 128 + (size_t)kt * 256 * 128;
    const bf16_t* Qg = Qb + (size_t)bh * 2048 * 128;
    const float* rlg = rl + (size_t)bh * 2048;
    const int rg = wave >> 1;           // resident col group (0..3)
    const int wcK = rg * 64;
    const int wq  = (wave & 1) * 32;    // streamed half-tile (q rows)

    int srow[2], scc[2]; uint32_t soff[2];
#pragma unroll
    for (int r = 0; r < 2; ++r) {
        int s = r * 512 + wave * 64 + lane;
        srow[r] = s >> 4; int j = s & 15;
        scc[r] = j ^ (srow[r] & 7);
        soff[r] = (uint32_t)(r * 512 + wave * 64) * 16;
    }
    // stage resident K (256 rows, 64 KiB) into buffers 0..3
#pragma unroll
    for (int b = 0; b < 4; ++b)
#pragma unroll
        for (int r = 0; r < 2; ++r)
            gll16(Kg + (size_t)(b * 64 + srow[r]) * 128 + scc[r] * 8,
                  smem + b * BUF + soff[r]);
    __syncthreads();
    const bf16_t* klds = (const bf16_t*)smem;
    bf16x8v kf[4][4];   // [kb][tk]
#pragma unroll
    for (int kb = 0; kb < 4; ++kb)
#pragma unroll
        for (int t = 0; t < 4; ++t) {
            int n = wcK + t * 16 + l15;   // 0..255
            kf[kb][t] = *reinterpret_cast<const bf16x8v*>(
                klds + n * 128 + ((kb * 4 + quad) ^ (n & 7)) * 8);
        }
    __syncthreads();
    // prologue: stage Q tiles 0,1,2 + their rl slices (3 vm-insts/wave/tile)
#pragma unroll
    for (int tt = 0; tt < 3; ++tt) {
#pragma unroll
        for (int r = 0; r < 2; ++r)
            gll16(Qg + (size_t)(tt * 64 + srow[r]) * 128 + scc[r] * 8,
                  smem + tt * BUF + soff[r]);
        if (lane < 2)
            gll16(rlg + tt * 64 + wave * 8 + lane * 4,
                  smem + RLOFF + tt * 256 + wave * 32);
    }

    float csum[4] = {};
    auto do_tile = [&](int t, bool stage_on) {
        WAITLG0();
        __builtin_amdgcn_s_barrier();
        FENCE();
        const bf16_t* cb = (const bf16_t*)(smem + (size_t)(t & 3) * BUF);
        if (stage_on) {
            char* tgt = smem + (size_t)((t + 3) & 3) * BUF;
#pragma unroll
            for (int r = 0; r < 2; ++r)
                gll16(Qg + (size_t)((t + 3) * 64 + srow[r]) * 128 + scc[r] * 8,
                      tgt + soff[r]);
            if (lane < 2)
                gll16(rlg + (t + 3) * 64 + wave * 8 + lane * 4,
                      smem + RLOFF + ((t + 3) & 3) * 256 + wave * 32);
        }
        f32x4v sc[2][4] = {};
#pragma unroll
        for (int kb = 0; kb < 4; ++kb) {
            int ccq = kb * 4 + quad;
            bf16x8v av[2];
#pragma unroll
            for (int ta = 0; ta < 2; ++ta) {
                int m = wq + ta * 16 + l15;   // 0..63 streamed q rows
                av[ta] = *reinterpret_cast<const bf16x8v*>(
                    cb + (m * 16 + (ccq ^ (m & 7))) * 8);
            }
            __builtin_amdgcn_s_setprio(1);
#pragma unroll
            for (int ta = 0; ta < 2; ++ta)
#pragma unroll
                for (int tk = 0; tk < 4; ++tk)
                    sc[ta][tk] = __builtin_amdgcn_mfma_f32_16x16x32_bf16(
                                     av[ta], kf[kb][tk], sc[ta][tk], 0, 0, 0);
            __builtin_amdgcn_s_setprio(0);
        }
#pragma unroll
        for (int ta = 0; ta < 2; ++ta) {
            f32x4v rlv = *reinterpret_cast<const f32x4v*>(
                smem + RLOFF + (t & 3) * 256 + (wq + ta * 16 + quad * 4) * 4);
#pragma unroll
            for (int r = 0; r < 4; ++r)
#pragma unroll
                for (int tk = 0; tk < 4; ++tk)
                    csum[tk] += __builtin_amdgcn_exp2f(sc[ta][tk][r]) * rlv[r];
        }
    };

    for (int t = 0; t < 29; ++t) {
        WAITVM(6);
        do_tile(t, true);
    }
    WAITVM(6); do_tile(29, false);
    WAITVM(3); do_tile(30, false);
    WAITVM(0); do_tile(31, false);

    // col-reduce across quads, then across sh wave pairs via LDS
    __syncthreads();
    float* cs_sh = (float*)smem;
    if (tid < 256) cs_sh[tid] = 0.f;
    __syncthreads();
#pragma unroll
    for (int tk = 0; tk < 4; ++tk) {
        float v = csum[tk];
        v += __shfl_xor(v, 16); v += __shfl_xor(v, 32);
        if (quad == 0) atomicAdd(&cs_sh[wcK + tk * 16 + l15], v);
    }
    __syncthreads();
    // fused: scale this block's disjoint 256x128 V patch in place
    int b = bh >> 4, h = bh & 15;
#pragma unroll
    for (int r = 0; r < 8; ++r) {
        int s = r * 512 + tid;
        int row = s >> 4, jc = s & 15;
        size_t off = ((size_t)(b * 2048 + kt * 256 + row)) * 2048 + h * 128 + jc * 8;
        float csv = cs_sh[row];
        bf16x8v vv = *reinterpret_cast<const bf16x8v*>(Vb + off);
        bf16x8v ov;
#pragma unroll
        for (int i = 0; i < 8; ++i) ov[i] = (__bf16)((float)vv[i] * csv);
        *reinterpret_cast<bf16x8v*>(Vb + off) = ov;
    }
}

// ---------------------------------------------------------------- launch
extern "C" void kernel_launch(void* const* d_in, const int* in_sizes, int n_in,
                              void* d_out, int out_size, void* d_ws, size_t ws_size,
                              hipStream_t stream) {
    (void)in_sizes; (void)n_in; (void)out_size; (void)ws_size;
    const float* x     = (const float*)d_in[0];
    const float* w_qkv = (const float*)d_in[1];
    const float* w_o   = (const float*)d_in[2];
    float* out = (float*)d_out;

    static int inited = 0;
    if (!inited) {
        (void)hipFuncSetAttribute((const void*)qkv8_k,
                                  hipFuncAttributeMaxDynamicSharedMemorySize, 114688);
        (void)hipFuncSetAttribute((const void*)attn_l_k,
                                  hipFuncAttributeMaxDynamicSharedMemorySize, 65536);
        (void)hipFuncSetAttribute((const void*)attn_cs_k,
                                  hipFuncAttributeMaxDynamicSharedMemorySize, 66560);
        inited = 1;
    }

    char* w = (char*)d_ws;
    auto alloc = [&](size_t bytes) {
        char* p = w; w += (bytes + 255) & ~(size_t)255; return p;
    };
    bf16_t* Xb    = (bf16_t*)alloc(4096ull * 2048 * 2);   // 16 MiB
    bf16_t* WqkvT = (bf16_t*)alloc(6144ull * 2048 * 2);   // 24 MiB
    bf16_t* WoT   = (bf16_t*)alloc(2048ull * 2048 * 2);   //  8 MiB
    bf16_t* Qb    = (bf16_t*)alloc(32ull * 2048 * 128 * 2); // 16 MiB [bh][s][d]
    bf16_t* Kb    = (bf16_t*)alloc(32ull * 2048 * 128 * 2);
    bf16_t* Vb    = (bf16_t*)alloc(4096ull * 2048 * 2);   // token-major
    float*  rlb   = (float*)alloc(32ull * 2048 * 4);      // 1/l (plain stores)

    conv_x_k <<<8192, 256, 0, stream>>>(x, Xb);
    conv_wT_k<<<dim3(192, 32), 256, 0, stream>>>(w_qkv, WqkvT, 2048, 6144);
    conv_wT_k<<<dim3(64, 32),  256, 0, stream>>>(w_o,   WoT,   2048, 2048);

    qkv8_k<<<dim3(32, 16), 512, 114688, stream>>>(Xb, WqkvT, Qb, Kb, Vb);

    attn_l_k <<<dim3(8, 32), 512, 65536, stream>>>(Qb, Kb, rlb);
    attn_cs_k<<<dim3(8, 32), 512, 66560, stream>>>(Qb, Kb, rlb, Vb);

    outg_k<<<dim3(16, 32), 256, 0, stream>>>(Vb, WoT, out);
}

// Round 7
// 364.634 us; speedup vs baseline: 1.0857x; 1.0857x over previous
//
#include <hip/hip_runtime.h>
#include <stdint.h>

// MegatronAttention: B=2, S=2048, H=2048, NH=16, DH=128.
// KEY INSIGHT: reference einsum 'bhqk,bhkd->bhkd' sums over q ->
//   values[b,h,k,d] = colsum_q(probs)[b,h,k] * v[b,h,k,d].
// Pipeline: convert->bf16, QKV GEMM (scatter epilogue, Q pre-scaled by
// 1/sqrt(d)*log2e), l-pass (writes 1/rowsum), cs-pass (weighted col sums
// + fused V scale), output GEMM.
// Anchor: qkv8 dispatch (106-109 us at normal clock) calibrates sessions.
// R11: attn-256 REFUTED at normal clock (rest 287 vs 250 for attn-128):
//   1 block/CU exposed every per-tile stall -> attn is latency/occupancy-
//   bound, NOT stream-BW-bound (halved traffic got slower).
// R12: attn-128 ring 4->3 buffers (48 KiB) -> 3 blocks/CU (12 waves/CU,
//   +50% co-resident waves to hide per-tile latency, m114), counted vmcnt
//   kept at depth-2 (stage t+2 during t, steady vmcnt(4)/(5)).
//   outg: proven BK=64 static drain 3/CU. qkv8 unchanged (R6).

typedef __bf16 bf16_t;
typedef __bf16 bf16x8v __attribute__((ext_vector_type(8)));
typedef __bf16 bf16x4v __attribute__((ext_vector_type(4)));
typedef float  f32x4v  __attribute__((ext_vector_type(4)));

#define DEVINL __device__ __forceinline__

// async global->LDS DMA, 16B per lane. LDS dest is wave-uniform base;
// HW writes lane i's data at base + i*16. Respects exec mask.
DEVINL void gll16(const void* g, void* lds_wave_uniform_base) {
    __builtin_amdgcn_global_load_lds(
        (__attribute__((address_space(1))) void*)g,
        (__attribute__((address_space(3))) void*)lds_wave_uniform_base,
        16, 0, 0);
}

#define WAITVM(n) asm volatile("s_waitcnt vmcnt(" #n ")" ::: "memory")
#define WAITLG0() asm volatile("s_waitcnt lgkmcnt(0)" ::: "memory")
#define FENCE()   asm volatile("" ::: "memory")

// ---------------------------------------------------------------- converts
__global__ void conv_x_k(const float* __restrict__ in, bf16_t* __restrict__ out) {
    size_t i = ((size_t)blockIdx.x * 256 + threadIdx.x) * 4;
    float4 v = *reinterpret_cast<const float4*>(in + i);
    bf16x4v o;
    o[0] = (__bf16)v.x; o[1] = (__bf16)v.y; o[2] = (__bf16)v.z; o[3] = (__bf16)v.w;
    *reinterpret_cast<bf16x4v*>(out + i) = o;
}

// out[n][k] = (bf16) in[k][n]   (in: K x N fp32, out: N x K bf16)
__global__ void conv_wT_k(const float* __restrict__ in, bf16_t* __restrict__ out,
                          int K, int N) {
    __shared__ float t[64][33];
    int n0 = blockIdx.x * 32, k0 = blockIdx.y * 64;
    int tn = threadIdx.x & 31, tk = threadIdx.x >> 5;   // tk in 0..7
#pragma unroll
    for (int i = 0; i < 64; i += 8)
        t[tk + i][tn] = in[(size_t)(k0 + tk + i) * N + n0 + tn];
    __syncthreads();
    int n = threadIdx.x >> 3, kg = threadIdx.x & 7;
    bf16x8v o;
#pragma unroll
    for (int i = 0; i < 8; ++i) o[i] = (__bf16)t[kg * 8 + i][n];
    *reinterpret_cast<bf16x8v*>(out + (size_t)(n0 + n) * K + k0 + kg * 8) = o;
}

// ---------------------------------------------------------------- QKV GEMM
// C[4096,6144] = Xb @ WqkvT^T. 256x192 tile, BK=32, 8 waves (2Mx4N),
// 4-buffer LDS ring (112 KiB), counted vmcnt(8), setprio. R6 proven form.
__launch_bounds__(512, 2)
__global__ void qkv8_k(const bf16_t* __restrict__ A, const bf16_t* __restrict__ Bm,
                       bf16_t* __restrict__ Qb, bf16_t* __restrict__ Kb,
                       bf16_t* __restrict__ Vb)
{
    extern __shared__ __align__(16) char smem[];   // 114688 B
    constexpr int K = 2048, NT = 64;               // K-tiles of 32
    constexpr int BUF = 28672;                     // 448*64 B per buffer
    const int tid  = threadIdx.x;
    const int lane = tid & 63, wave = tid >> 6;
    const int quad = lane >> 4, l15 = lane & 15;
    const int rowBase = blockIdx.y * 256, colBase = blockIdx.x * 192;
    const int wr = wave >> 2, wc = wave & 3;
    const bool stager = (wave < 7);                // threads 0..447

    const bf16_t* sp[4]; uint32_t sdo[4];
#pragma unroll
    for (int r = 0; r < 4; ++r) {
        int row = r * 112 + (tid >> 2);
        if (row > 447) row = 447;
        int j  = tid & 3;
        int cc = j ^ ((row >> 1) & 3);
        const bf16_t* base = (row < 256)
            ? (A  + (size_t)(rowBase + row) * K)
            : (Bm + (size_t)(colBase + row - 256) * K);
        sp[r]  = base + cc * 8;
        sdo[r] = (uint32_t)(r * 7168 + wave * 1024);
    }
    uint32_t aoff[8], boff[3];
#pragma unroll
    for (int ti = 0; ti < 8; ++ti) {
        int m = wr * 128 + ti * 16 + l15;
        aoff[ti] = (uint32_t)(m * 64 + ((quad ^ ((m >> 1) & 3)) << 4));
    }
#pragma unroll
    for (int tj = 0; tj < 3; ++tj) {
        int rb = 256 + wc * 48 + tj * 16 + l15;
        boff[tj] = (uint32_t)(rb * 64 + ((quad ^ ((rb >> 1) & 3)) << 4));
    }

    if (stager) {
#pragma unroll
        for (int tt = 0; tt < 3; ++tt)
#pragma unroll
            for (int r = 0; r < 4; ++r)
                gll16(sp[r] + tt * 32, smem + tt * BUF + sdo[r]);
    }

    f32x4v acc[8][3] = {};

    auto do_tile = [&](int t, bool stage_on) {
        WAITLG0();
        __builtin_amdgcn_s_barrier();
        FENCE();
        const char* bp = smem + (size_t)(t & 3) * BUF;
        char*       np = smem + (size_t)((t + 3) & 3) * BUF;
        if (stage_on && stager) {
            gll16(sp[0] + (t + 3) * 32, np + sdo[0]);
            gll16(sp[1] + (t + 3) * 32, np + sdo[1]);
        }
        bf16x8v bv[3], av[4];
#pragma unroll
        for (int tj = 0; tj < 3; ++tj) bv[tj] = *(const bf16x8v*)(bp + boff[tj]);
#pragma unroll
        for (int ti = 0; ti < 4; ++ti) av[ti] = *(const bf16x8v*)(bp + aoff[ti]);
        __builtin_amdgcn_s_setprio(1);
#pragma unroll
        for (int ti = 0; ti < 4; ++ti)
#pragma unroll
            for (int tj = 0; tj < 3; ++tj)
                acc[ti][tj] = __builtin_amdgcn_mfma_f32_16x16x32_bf16(
                                  av[ti], bv[tj], acc[ti][tj], 0, 0, 0);
        __builtin_amdgcn_s_setprio(0);
        if (stage_on && stager) {
            gll16(sp[2] + (t + 3) * 32, np + sdo[2]);
            gll16(sp[3] + (t + 3) * 32, np + sdo[3]);
        }
#pragma unroll
        for (int ti = 0; ti < 4; ++ti) av[ti] = *(const bf16x8v*)(bp + aoff[4 + ti]);
        __builtin_amdgcn_s_setprio(1);
#pragma unroll
        for (int ti = 0; ti < 4; ++ti)
#pragma unroll
            for (int tj = 0; tj < 3; ++tj)
                acc[4 + ti][tj] = __builtin_amdgcn_mfma_f32_16x16x32_bf16(
                                      av[ti], bv[tj], acc[4 + ti][tj], 0, 0, 0);
        __builtin_amdgcn_s_setprio(0);
    };

    for (int t = 0; t < NT - 2; ++t) {
        WAITVM(8);
        do_tile(t, t < NT - 3);
    }
    WAITVM(4);
    do_tile(NT - 2, false);
    WAITVM(0);
    do_tile(NT - 1, false);

    constexpr float QS = 0.08838834764831845f * 1.44269504088896341f;
#pragma unroll
    for (int ti = 0; ti < 8; ++ti)
#pragma unroll
        for (int tj = 0; tj < 3; ++tj)
#pragma unroll
            for (int r = 0; r < 4; ++r) {
                int m = rowBase + wr * 128 + ti * 16 + quad * 4 + r;
                int n = colBase + wc * 48 + tj * 16 + l15;
                float v = acc[ti][tj][r];
                int b = m >> 11, s = m & 2047;
                int which = n >> 11, hd = n & 2047;
                if (which == 2) {
                    Vb[(size_t)m * 2048 + hd] = (__bf16)v;        // token-major
                } else {
                    if (which == 0) v *= QS;                      // fold softmax scale
                    size_t idx = ((size_t)((b << 4) + (hd >> 7)) * 2048 + s) * 128
                                 + (hd & 127);
                    if (which == 0) Qb[idx] = (__bf16)v; else Kb[idx] = (__bf16)v;
                }
            }
}

// ---------------------------------------------------------------- out GEMM
// Proven R5/R8 form: 128x128 tile, BK=64, static 32 KiB LDS, 3 blocks/CU,
// drain barriers. C[4096,2048] = Vb @ WoT^T, fp32 out.
__launch_bounds__(256, 3)
__global__ void outg_k(const bf16_t* __restrict__ A, const bf16_t* __restrict__ Bm,
                       float* __restrict__ outF)
{
    __shared__ __align__(16) bf16_t sA[128 * 64];   // 16 KiB
    __shared__ __align__(16) bf16_t sB[128 * 64];
    constexpr int K = 2048;
    const int tid  = threadIdx.x;
    const int lane = tid & 63, wave = tid >> 6;
    const int quad = lane >> 4, l15 = lane & 15;
    const int rowBase = blockIdx.y * 128, colBase = blockIdx.x * 128;
    const int wr0 = (wave >> 1) * 64, wc0 = (wave & 1) * 64;

    const bf16_t* gA[4]; const bf16_t* gB[4]; uint32_t loff[4];
#pragma unroll
    for (int r = 0; r < 4; ++r) {
        int s = r * 256 + wave * 64 + lane;
        int row = s >> 3, j = s & 7;
        int cc = j ^ (row & 7);
        gA[r] = A  + (size_t)(rowBase + row) * K + cc * 8;
        gB[r] = Bm + (size_t)(colBase + row) * K + cc * 8;
        loff[r] = (uint32_t)(r * 256 + wave * 64) * 16;
    }
    int aoff[2][4], boff[2][4];   // [kstep][t] LDS elem offsets
#pragma unroll
    for (int ks = 0; ks < 2; ++ks)
#pragma unroll
        for (int t = 0; t < 4; ++t) {
            int m = wr0 + t * 16 + l15;
            aoff[ks][t] = (m * 8 + ((ks * 4 + quad) ^ (m & 7))) * 8;
            int n = wc0 + t * 16 + l15;
            boff[ks][t] = (n * 8 + ((ks * 4 + quad) ^ (n & 7))) * 8;
        }

    f32x4v acc[4][4] = {};
    for (int kt = 0; kt < K / 64; ++kt) {
        __syncthreads();
#pragma unroll
        for (int r = 0; r < 4; ++r) {
            gll16(gA[r] + kt * 64, (char*)sA + loff[r]);
            gll16(gB[r] + kt * 64, (char*)sB + loff[r]);
        }
        __syncthreads();
#pragma unroll
        for (int ks = 0; ks < 2; ++ks) {
            bf16x8v av[4], bv[4];
#pragma unroll
            for (int t = 0; t < 4; ++t) av[t] = *reinterpret_cast<const bf16x8v*>(sA + aoff[ks][t]);
#pragma unroll
            for (int t = 0; t < 4; ++t) bv[t] = *reinterpret_cast<const bf16x8v*>(sB + boff[ks][t]);
#pragma unroll
            for (int ti = 0; ti < 4; ++ti)
#pragma unroll
                for (int tj = 0; tj < 4; ++tj)
                    acc[ti][tj] = __builtin_amdgcn_mfma_f32_16x16x32_bf16(
                                      av[ti], bv[tj], acc[ti][tj], 0, 0, 0);
        }
    }

#pragma unroll
    for (int ti = 0; ti < 4; ++ti)
#pragma unroll
        for (int tj = 0; tj < 4; ++tj)
#pragma unroll
            for (int r = 0; r < 4; ++r) {
                int m = rowBase + wr0 + ti * 16 + quad * 4 + r;
                int n = colBase + wc0 + tj * 16 + l15;
                outF[(size_t)m * 2048 + n] = acc[ti][tj][r];
            }
}

// ---------------------------------------------------------------- attention
// R12: 128 resident rows (frags in VGPR), sweep 2048 streamed rows in
// 32 x 64-row tiles through a RING-3 (48 KiB) with counted vmcnt depth-2
// (stage t+2 during t, steady vmcnt(4)). 3 blocks/CU = 12 waves/CU.
// Swizzle: 16 chunks of 16B per 256B row, cc = j ^ (row&7).

__launch_bounds__(256, 3)
__global__ void attn_l_k(const bf16_t* __restrict__ Qb, const bf16_t* __restrict__ Kb,
                         float* __restrict__ rl)
{
    extern __shared__ __align__(16) char smem[];   // 3 x 16384 = 49152 B
    constexpr int BUF = 16384;
    const int tid  = threadIdx.x;
    const int lane = tid & 63, wave = tid >> 6;
    const int quad = lane >> 4, l15 = lane & 15;
    const int qt = blockIdx.x, bh = blockIdx.y;
    const bf16_t* Qg = Qb + (size_t)bh * 2048 * 128 + (size_t)qt * 128 * 128;
    const bf16_t* Kg = Kb + (size_t)bh * 2048 * 128;
    const int wr0 = (wave >> 1) * 64;   // resident q rows
    const int wc0 = (wave & 1) * 32;    // streamed half-tile

    int srow[4], scc[4]; uint32_t soff[4];
#pragma unroll
    for (int r = 0; r < 4; ++r) {
        int s = r * 256 + wave * 64 + lane;
        srow[r] = s >> 4; int j = s & 15;
        scc[r] = j ^ (srow[r] & 7);
        soff[r] = (uint32_t)(r * 256 + wave * 64) * 16;
    }
    // stage resident Q (128 rows, 32 KiB) into buffers 0,1 (contiguous)
#pragma unroll
    for (int r = 0; r < 4; ++r) {
        gll16(Qg + (size_t)srow[r] * 128 + scc[r] * 8, smem + soff[r]);
        gll16(Qg + (size_t)(64 + srow[r]) * 128 + scc[r] * 8, smem + BUF + soff[r]);
    }
    __syncthreads();
    const bf16_t* qlds = (const bf16_t*)smem;
    bf16x8v qf[4][4];   // [kb][ti] : 64 VGPR, invariant over the sweep
#pragma unroll
    for (int kb = 0; kb < 4; ++kb)
#pragma unroll
        for (int t = 0; t < 4; ++t) {
            int m = wr0 + t * 16 + l15;   // 0..127
            qf[kb][t] = *reinterpret_cast<const bf16x8v*>(
                qlds + (m * 16 + ((kb * 4 + quad) ^ (m & 7))) * 8);
        }
    __syncthreads();    // Q reads drained before K overwrites
    // prologue: stage K tiles 0,1 (ring-3 keeps 2 tiles in flight)
#pragma unroll
    for (int tt = 0; tt < 2; ++tt)
#pragma unroll
        for (int r = 0; r < 4; ++r)
            gll16(Kg + (size_t)(tt * 64 + srow[r]) * 128 + scc[r] * 8,
                  smem + tt * BUF + soff[r]);

    float lsum[4][4] = {};
    auto do_tile = [&](int t, int cb, bool stage_on) {
        WAITLG0();
        __builtin_amdgcn_s_barrier();
        FENCE();
        const bf16_t* cbuf = (const bf16_t*)(smem + (size_t)cb * BUF);
        if (stage_on) {
            int nb = cb + 2; if (nb >= 3) nb -= 3;
            char* tgt = smem + (size_t)nb * BUF;
#pragma unroll
            for (int r = 0; r < 4; ++r)
                gll16(Kg + (size_t)((t + 2) * 64 + srow[r]) * 128 + scc[r] * 8,
                      tgt + soff[r]);
        }
        f32x4v sc[4][2] = {};
#pragma unroll
        for (int kb = 0; kb < 4; ++kb) {
            int ccq = kb * 4 + quad;
            bf16x8v bv[2];
#pragma unroll
            for (int tj = 0; tj < 2; ++tj) {
                int n = wc0 + tj * 16 + l15;   // 0..63
                bv[tj] = *reinterpret_cast<const bf16x8v*>(
                    cbuf + (n * 16 + (ccq ^ (n & 7))) * 8);
            }
            __builtin_amdgcn_s_setprio(1);
#pragma unroll
            for (int ti = 0; ti < 4; ++ti)
#pragma unroll
                for (int tj = 0; tj < 2; ++tj)
                    sc[ti][tj] = __builtin_amdgcn_mfma_f32_16x16x32_bf16(
                                     qf[kb][ti], bv[tj], sc[ti][tj], 0, 0, 0);
            __builtin_amdgcn_s_setprio(0);
        }
#pragma unroll
        for (int ti = 0; ti < 4; ++ti)
#pragma unroll
            for (int r = 0; r < 4; ++r)
                lsum[ti][r] += __builtin_amdgcn_exp2f(sc[ti][0][r])
                             + __builtin_amdgcn_exp2f(sc[ti][1][r]);
    };

    int cb = 0;
    for (int t = 0; t < 30; ++t) {
        WAITVM(4);                      // K(t) landed; K(t+1) in flight
        do_tile(t, cb, t < 30 - 0 - 0 && t <= 29);   // stage K(t+2) for t<=29
        cb = (cb + 1 == 3) ? 0 : cb + 1;
    }
    WAITVM(4); do_tile(30, cb, false);
    cb = (cb + 1 == 3) ? 0 : cb + 1;
    WAITVM(0); do_tile(31, cb, false);

    // reduce across l15 (cols) then across wave pairs (streamed halves)
    __syncthreads();
    float* l_sh = (float*)smem;
    if (tid < 128) l_sh[tid] = 0.f;
    __syncthreads();
#pragma unroll
    for (int ti = 0; ti < 4; ++ti)
#pragma unroll
        for (int r = 0; r < 4; ++r) {
            float v = lsum[ti][r];
            v += __shfl_xor(v, 1); v += __shfl_xor(v, 2);
            v += __shfl_xor(v, 4); v += __shfl_xor(v, 8);
            if (l15 == 0) atomicAdd(&l_sh[wr0 + ti * 16 + quad * 4 + r], v);
        }
    __syncthreads();
    if (tid < 128)
        rl[(size_t)bh * 2048 + qt * 128 + tid] = 1.0f / l_sh[tid];
}

__launch_bounds__(256, 3)
__global__ void attn_cs_k(const bf16_t* __restrict__ Qb, const bf16_t* __restrict__ Kb,
                          const float* __restrict__ rl, bf16_t* __restrict__ Vb)
{
    // layout: [0,49152) = 3 x 16 KiB Q-tile ring; [49152,49920) = 3 x 256B rl ring
    extern __shared__ __align__(16) char smem[];
    constexpr int BUF = 16384, RLOFF = 49152;
    const int tid  = threadIdx.x;
    const int lane = tid & 63, wave = tid >> 6;
    const int quad = lane >> 4, l15 = lane & 15;
    const int kt = blockIdx.x, bh = blockIdx.y;
    const bf16_t* Kg = Kb + (size_t)bh * 2048 * 128 + (size_t)kt * 128 * 128;
    const bf16_t* Qg = Qb + (size_t)bh * 2048 * 128;
    const float* rlg = rl + (size_t)bh * 2048;
    const int wcK = (wave >> 1) * 64;   // resident k cols
    const int wq  = (wave & 1) * 32;    // streamed half-tile (q rows)

    int srow[4], scc[4]; uint32_t soff[4];
#pragma unroll
    for (int r = 0; r < 4; ++r) {
        int s = r * 256 + wave * 64 + lane;
        srow[r] = s >> 4; int j = s & 15;
        scc[r] = j ^ (srow[r] & 7);
        soff[r] = (uint32_t)(r * 256 + wave * 64) * 16;
    }
    // stage resident K (128 rows, 32 KiB) into buffers 0,1
#pragma unroll
    for (int r = 0; r < 4; ++r) {
        gll16(Kg + (size_t)srow[r] * 128 + scc[r] * 8, smem + soff[r]);
        gll16(Kg + (size_t)(64 + srow[r]) * 128 + scc[r] * 8, smem + BUF + soff[r]);
    }
    __syncthreads();
    const bf16_t* klds = (const bf16_t*)smem;
    bf16x8v kf[4][4];   // [kb][tk]
#pragma unroll
    for (int kb = 0; kb < 4; ++kb)
#pragma unroll
        for (int t = 0; t < 4; ++t) {
            int n = wcK + t * 16 + l15;   // 0..127
            kf[kb][t] = *reinterpret_cast<const bf16x8v*>(
                klds + (n * 16 + ((kb * 4 + quad) ^ (n & 7))) * 8);
        }
    __syncthreads();
    // prologue: stage Q tiles 0,1 + their rl slices (5 vm-insts/wave/tile)
#pragma unroll
    for (int tt = 0; tt < 2; ++tt) {
#pragma unroll
        for (int r = 0; r < 4; ++r)
            gll16(Qg + (size_t)(tt * 64 + srow[r]) * 128 + scc[r] * 8,
                  smem + tt * BUF + soff[r]);
        if (lane < 4)
            gll16(rlg + tt * 64 + wave * 16 + lane * 4,
                  smem + RLOFF + tt * 256 + wave * 64);
    }

    float csum[4] = {};
    auto do_tile = [&](int t, int cb, bool stage_on) {
        WAITLG0();
        __builtin_amdgcn_s_barrier();
        FENCE();
        const bf16_t* cbuf = (const bf16_t*)(smem + (size_t)cb * BUF);
        if (stage_on) {
            int nb = cb + 2; if (nb >= 3) nb -= 3;
            char* tgt = smem + (size_t)nb * BUF;
#pragma unroll
            for (int r = 0; r < 4; ++r)
                gll16(Qg + (size_t)((t + 2) * 64 + srow[r]) * 128 + scc[r] * 8,
                      tgt + soff[r]);
            if (lane < 4)
                gll16(rlg + (t + 2) * 64 + wave * 16 + lane * 4,
                      smem + RLOFF + nb * 256 + wave * 64);
        }
        f32x4v sc[2][4] = {};
#pragma unroll
        for (int kb = 0; kb < 4; ++kb) {
            int ccq = kb * 4 + quad;
            bf16x8v av[2];
#pragma unroll
            for (int ta = 0; ta < 2; ++ta) {
                int m = wq + ta * 16 + l15;   // 0..63 streamed q rows
                av[ta] = *reinterpret_cast<const bf16x8v*>(
                    cbuf + (m * 16 + (ccq ^ (m & 7))) * 8);
            }
            __builtin_amdgcn_s_setprio(1);
#pragma unroll
            for (int ta = 0; ta < 2; ++ta)
#pragma unroll
                for (int tk = 0; tk < 4; ++tk)
                    sc[ta][tk] = __builtin_amdgcn_mfma_f32_16x16x32_bf16(
                                     av[ta], kf[kb][tk], sc[ta][tk], 0, 0, 0);
            __builtin_amdgcn_s_setprio(0);
        }
#pragma unroll
        for (int ta = 0; ta < 2; ++ta) {
            f32x4v rlv = *reinterpret_cast<const f32x4v*>(
                smem + RLOFF + cb * 256 + (wq + ta * 16 + quad * 4) * 4);
#pragma unroll
            for (int r = 0; r < 4; ++r)
#pragma unroll
                for (int tk = 0; tk < 4; ++tk)
                    csum[tk] += __builtin_amdgcn_exp2f(sc[ta][tk][r]) * rlv[r];
        }
    };

    int cb = 0;
    for (int t = 0; t < 30; ++t) {
        WAITVM(5);                      // Q(t)+rl(t) landed; t+1 in flight
        do_tile(t, cb, t <= 29);
        cb = (cb + 1 == 3) ? 0 : cb + 1;
    }
    WAITVM(5); do_tile(30, cb, false);
    cb = (cb + 1 == 3) ? 0 : cb + 1;
    WAITVM(0); do_tile(31, cb, false);

    // col-reduce across quads, then across wave pairs via LDS
    __syncthreads();
    float* cs_sh = (float*)smem;
    if (tid < 128) cs_sh[tid] = 0.f;
    __syncthreads();
#pragma unroll
    for (int tk = 0; tk < 4; ++tk) {
        float v = csum[tk];
        v += __shfl_xor(v, 16); v += __shfl_xor(v, 32);
        if (quad == 0) atomicAdd(&cs_sh[wcK + tk * 16 + l15], v);
    }
    __syncthreads();
    // fused: scale this block's disjoint 128x128 V patch in place
    int b = bh >> 4, h = bh & 15;
#pragma unroll
    for (int r = 0; r < 8; ++r) {
        int s = r * 256 + tid;
        int row = s >> 4, jc = s & 15;
        size_t off = ((size_t)(b * 2048 + kt * 128 + row)) * 2048 + h * 128 + jc * 8;
        float csv = cs_sh[row];
        bf16x8v vv = *reinterpret_cast<const bf16x8v*>(Vb + off);
        bf16x8v ov;
#pragma unroll
        for (int i = 0; i < 8; ++i) ov[i] = (__bf16)((float)vv[i] * csv);
        *reinterpret_cast<bf16x8v*>(Vb + off) = ov;
    }
}

// ---------------------------------------------------------------- launch
extern "C" void kernel_launch(void* const* d_in, const int* in_sizes, int n_in,
                              void* d_out, int out_size, void* d_ws, size_t ws_size,
                              hipStream_t stream) {
    (void)in_sizes; (void)n_in; (void)out_size; (void)ws_size;
    const float* x     = (const float*)d_in[0];
    const float* w_qkv = (const float*)d_in[1];
    const float* w_o   = (const float*)d_in[2];
    float* out = (float*)d_out;

    static int inited = 0;
    if (!inited) {
        (void)hipFuncSetAttribute((const void*)qkv8_k,
                                  hipFuncAttributeMaxDynamicSharedMemorySize, 114688);
        (void)hipFuncSetAttribute((const void*)attn_l_k,
                                  hipFuncAttributeMaxDynamicSharedMemorySize, 49152);
        (void)hipFuncSetAttribute((const void*)attn_cs_k,
                                  hipFuncAttributeMaxDynamicSharedMemorySize, 49920);
        inited = 1;
    }

    char* w = (char*)d_ws;
    auto alloc = [&](size_t bytes) {
        char* p = w; w += (bytes + 255) & ~(size_t)255; return p;
    };
    bf16_t* Xb    = (bf16_t*)alloc(4096ull * 2048 * 2);   // 16 MiB
    bf16_t* WqkvT = (bf16_t*)alloc(6144ull * 2048 * 2);   // 24 MiB
    bf16_t* WoT   = (bf16_t*)alloc(2048ull * 2048 * 2);   //  8 MiB
    bf16_t* Qb    = (bf16_t*)alloc(32ull * 2048 * 128 * 2); // 16 MiB [bh][s][d]
    bf16_t* Kb    = (bf16_t*)alloc(32ull * 2048 * 128 * 2);
    bf16_t* Vb    = (bf16_t*)alloc(4096ull * 2048 * 2);   // token-major
    float*  rlb   = (float*)alloc(32ull * 2048 * 4);      // 1/l (plain stores)

    conv_x_k <<<8192, 256, 0, stream>>>(x, Xb);
    conv_wT_k<<<dim3(192, 32), 256, 0, stream>>>(w_qkv, WqkvT, 2048, 6144);
    conv_wT_k<<<dim3(64, 32),  256, 0, stream>>>(w_o,   WoT,   2048, 2048);

    qkv8_k<<<dim3(32, 16), 512, 114688, stream>>>(Xb, WqkvT, Qb, Kb, Vb);

    attn_l_k <<<dim3(16, 32), 256, 49152, stream>>>(Qb, Kb, rlb);
    attn_cs_k<<<dim3(16, 32), 256, 49920, stream>>>(Qb, Kb, rlb, Vb);

    outg_k<<<dim3(16, 32), 256, 0, stream>>>(Vb, WoT, out);
}